// Round 4
// baseline (126.495 us; speedup 1.0000x reference)
//
#include <hip/hip_runtime.h>

// out[b,o] = sum_i silu(x)*BW + ((xs^2-1)*exp(-xs^2/2))*WW + bias,  xs=(x-T)/S
// ROUND 10: occupancy 2 -> 4 blocks/CU.  R9 post-mortem: VALU busy-time
// (28.7us) == computed issue floor (4 pk*4cyc + 2 exp*8cyc per k-pair ->
// 27.3us); the 22us gap is un-hidden LDS/barrier/staging latency at only
// 2 waves/SIMD.  Fix via TLP, not ILP:
//   - BT 128->64 (4x4 acc/thread; the 8x4 tile's LDS win is moot now that
//     lsx/lb f32 reads are gone), grid 16x8x8 = 1024 = 4 blocks/CU
//   - lout (epilogue MFMA-merge buffer) ALIASES lx/la/lm/ln behind a barrier
//     -> LDS 71680 -> 30720 B (4 blocks = 122.9KB/CU)
//   - __launch_bounds__(256,4); acc halves -> ~100 VGPR < 128 cap
// Base branch on matrix pipe (v_mfma_f32_16x16x16f16, verified R9), wavelet
// math verified since round 2:
//   a2 = C2/s^2, m1 = -2*a2*t, m2' = a2*t^2 - C2, q = w * 2^C2 / C2
//   p = a2*x^2 + m1*x + m2';  contribution = p * q * 2^p,  C2 = -0.5*log2(e)

constexpr int IN_F  = 512;
constexpr int OUT_F = 512;
constexpr int BATCH = 1024;
constexpr int BT = 64, OT = 64;     // block tile
constexpr int KS = 8;               // k-split -> grid 16x8x8 = 1024 blocks
constexpr int KR = IN_F / KS;       // 64 k per block
constexpr int IT = 16;              // k chunk in LDS
constexpr int PITCH = IT + 4;       // f32 rows: 16B-aligned, 2-way banks (free)
constexpr int HP = IT + 4;          // f16 rows: 40B stride, conflict-free b64
constexpr int LP = OT + 1;          // epilogue merge pitch
constexpr int NCH = KR / IT;        // 4 chunks
constexpr int BO  = BATCH * OUT_F;  // 524288

#define LOG2E 1.44269504088897f
#define C2f   (-0.72134752044448f)
#define NC2f  ( 0.72134752044448f)
#define RQf   (-0.84083003f)   /* 2^C2 / C2 = e^{-1/2}/C2 */

typedef float v2f   __attribute__((ext_vector_type(2)));
typedef float f32x4 __attribute__((ext_vector_type(4)));
typedef _Float16 half4 __attribute__((ext_vector_type(4)));

__device__ __forceinline__ float fexp2(float v) { return __builtin_amdgcn_exp2f(v); }
__device__ __forceinline__ float frcp(float v)  { return __builtin_amdgcn_rcpf(v); }
__device__ __forceinline__ v2f pkfma(v2f a, v2f b, v2f c) {
  return __builtin_elementwise_fma(a, b, c);
}
__device__ __forceinline__ float fsilu(float v) {
  return v * frcp(1.f + fexp2(v * -LOG2E));
}

// LDS carve (floats):
//   lx   [   0..1279]  x tile, f32, 64x20
//   la   [1280..2559]  lm [2560..3839]  ln [3840..5119]  lq [5120..6399]
//   hx   [6400..7039]  silu(x) f16 64x20 (MFMA A)
//   hb   [7040..7679]  basew   f16 64x20 (MFMA B)
//   lout [   0..4159]  ALIAS of lx/la/lm/ln: epilogue merge 64x65 (after barrier)
constexpr int SMEM_F = 7680;        // 30720 B

__global__ __launch_bounds__(256, 4)
void wkan_main(const float* __restrict__ x, const float* __restrict__ basew,
               const float* __restrict__ wavew, const float* __restrict__ scale,
               const float* __restrict__ transl, const float* __restrict__ bias,
               float* __restrict__ partial, float* __restrict__ out, int use_ws)
{
  __shared__ float smem[SMEM_F];
  float* lx = smem;
  float* la = smem + 1280;
  float* lm = smem + 2560;
  float* ln = smem + 3840;
  float* lq = smem + 5120;
  _Float16* hx = (_Float16*)(smem + 6400);
  _Float16* hb = (_Float16*)(smem + 7040);
  float* lout = smem;               // epilogue alias

  const int tid = threadIdx.x;
  const int b0 = blockIdx.x * BT;
  const int o0 = blockIdx.y * OT;
  const int ks = blockIdx.z;
  const int k0 = ks * KR;

  const int srow = tid >> 2;        // 0..63 staging row
  const int sc4  = (tid & 3) * 4;   // 0,4,8,12
  const int lofs = srow * PITCH + sc4;
  const int hofs = srow * HP + sc4;

  const int to = tid & 15;          // output col group (cols to + 16c)
  const int tb = tid >> 4;          // output row group 0..15 (rows tb + 16r)

  const int lane = tid & 63;
  const int wid  = tid >> 6;        // wave 0..3 -> m-tile rows wid*16..wid*16+15
  const int frow = lane & 15;       // m/n within MFMA tile
  const int kgrp = (lane >> 4) * 4; // k group within chunk

  v2f zz; zz.x = 0.f; zz.y = 0.f;
  v2f acc[4][4];
#pragma unroll
  for (int r = 0; r < 4; ++r)
#pragma unroll
    for (int c = 0; c < 4; ++c) acc[r][c] = zz;

  f32x4 accb[4];                    // base-GEMM fragments: 4 n-tiles
#pragma unroll
  for (int nt = 0; nt < 4; ++nt) accb[nt] = (f32x4)0.f;

  // prefetch registers (T14: live across the compute phase)
  float4 xv, sv, tv, wv, bv;
  {
    const int g = k0 + sc4;
    xv = *(const float4*)(x      + (size_t)(b0 + srow) * IN_F + g);
    sv = *(const float4*)(scale  + (size_t)(o0 + srow) * IN_F + g);
    tv = *(const float4*)(transl + (size_t)(o0 + srow) * IN_F + g);
    wv = *(const float4*)(wavew  + (size_t)(o0 + srow) * IN_F + g);
    bv = *(const float4*)(basew  + (size_t)(o0 + srow) * IN_F + g);
  }

  for (int kc = 0; kc < NCH; ++kc) {
    if (kc) __syncthreads();          // prev-chunk readers done
    // ---------- transform prefetched regs -> LDS ----------
    {
      float4 sx;
      sx.x = fsilu(xv.x); sx.y = fsilu(xv.y); sx.z = fsilu(xv.z); sx.w = fsilu(xv.w);
      *(float4*)(lx + lofs) = xv;
      half4 h0;
      h0[0] = (_Float16)sx.x; h0[1] = (_Float16)sx.y;
      h0[2] = (_Float16)sx.z; h0[3] = (_Float16)sx.w;
      *(half4*)(hx + hofs) = h0;

      float4 av, mv, nv;
      {
        float a2, a2t;
        a2 = C2f * frcp(sv.x * sv.x); a2t = a2 * tv.x;
        av.x = a2; mv.x = -2.f * a2t; nv.x = fmaf(a2t, tv.x, NC2f);
        a2 = C2f * frcp(sv.y * sv.y); a2t = a2 * tv.y;
        av.y = a2; mv.y = -2.f * a2t; nv.y = fmaf(a2t, tv.y, NC2f);
        a2 = C2f * frcp(sv.z * sv.z); a2t = a2 * tv.z;
        av.z = a2; mv.z = -2.f * a2t; nv.z = fmaf(a2t, tv.z, NC2f);
        a2 = C2f * frcp(sv.w * sv.w); a2t = a2 * tv.w;
        av.w = a2; mv.w = -2.f * a2t; nv.w = fmaf(a2t, tv.w, NC2f);
      }
      *(float4*)(la + lofs) = av;
      *(float4*)(lm + lofs) = mv;
      *(float4*)(ln + lofs) = nv;

      float4 qv;
      qv.x = wv.x * RQf; qv.y = wv.y * RQf; qv.z = wv.z * RQf; qv.w = wv.w * RQf;
      *(float4*)(lq + lofs) = qv;

      half4 hbv;
      hbv[0] = (_Float16)bv.x; hbv[1] = (_Float16)bv.y;
      hbv[2] = (_Float16)bv.z; hbv[3] = (_Float16)bv.w;
      *(half4*)(hb + hofs) = hbv;
    }
    __syncthreads();                  // chunk kc ready in LDS

    // ---------- issue next chunk's global loads (hide under compute) -------
    if (kc + 1 < NCH) {
      const int g = k0 + (kc + 1) * IT + sc4;
      xv = *(const float4*)(x      + (size_t)(b0 + srow) * IN_F + g);
      sv = *(const float4*)(scale  + (size_t)(o0 + srow) * IN_F + g);
      tv = *(const float4*)(transl + (size_t)(o0 + srow) * IN_F + g);
      wv = *(const float4*)(wavew  + (size_t)(o0 + srow) * IN_F + g);
      bv = *(const float4*)(basew  + (size_t)(o0 + srow) * IN_F + g);
    }

    // ---------- base branch: 4 MFMA on the matrix pipe ----------
    {
      half4 af = *(const half4*)(hx + (wid * 16 + frow) * HP + kgrp);
#pragma unroll
      for (int nt = 0; nt < 4; ++nt) {
        half4 bf = *(const half4*)(hb + (nt * 16 + frow) * HP + kgrp);
        accb[nt] = __builtin_amdgcn_mfma_f32_16x16x16f16(af, bf, accb[nt], 0, 0, 0);
      }
    }

    // ---------- wavelet: 4x4 outputs/thread on the VALU ----------
    for (int ii = 0; ii < IT; ii += 4) {
      float4 xr[4], x2[4];
#pragma unroll
      for (int r = 0; r < 4; ++r) {
        const int row = (tb + 16 * r) * PITCH + ii;
        xr[r] = *(const float4*)(lx + row);
        x2[r].x = xr[r].x * xr[r].x;
        x2[r].y = xr[r].y * xr[r].y;
        x2[r].z = xr[r].z * xr[r].z;
        x2[r].w = xr[r].w * xr[r].w;
      }
#pragma unroll
      for (int c = 0; c < 4; ++c) {
        const int orow = (to + 16 * c) * PITCH + ii;
        float4 A = *(const float4*)(la + orow);
        float4 M = *(const float4*)(lm + orow);
        float4 N = *(const float4*)(ln + orow);
        float4 Q = *(const float4*)(lq + orow);
        v2f Al = {A.x, A.y}, Ah = {A.z, A.w};
        v2f Ml = {M.x, M.y}, Mh = {M.z, M.w};
        v2f Nl = {N.x, N.y}, Nh = {N.z, N.w};
        v2f Ql = {Q.x, Q.y}, Qh = {Q.z, Q.w};
#pragma unroll
        for (int r = 0; r < 4; ++r) {
          v2f xl  = {xr[r].x, xr[r].y}, xh  = {xr[r].z, xr[r].w};
          v2f x2l = {x2[r].x, x2[r].y}, x2h = {x2[r].z, x2[r].w};
          v2f p, e, gg;
          p = pkfma(Al, x2l, pkfma(Ml, xl, Nl));
          e.x = fexp2(p.x); e.y = fexp2(p.y);
          gg = p * Ql;
          acc[r][c] = pkfma(gg, e, acc[r][c]);
          p = pkfma(Ah, x2h, pkfma(Mh, xh, Nh));
          e.x = fexp2(p.x); e.y = fexp2(p.y);
          gg = p * Qh;
          acc[r][c] = pkfma(gg, e, acc[r][c]);
        }
      }
    }
  }

  // ---------- epilogue: merge base fragments with wavelet acc ----------
  __syncthreads();                  // all LDS tile reads done; lout may alias
  // D layout: n = lane&15, m = (lane>>4)*4 + i   (within each 16x16 tile)
#pragma unroll
  for (int nt = 0; nt < 4; ++nt)
#pragma unroll
    for (int i = 0; i < 4; ++i)
      lout[(wid * 16 + (lane >> 4) * 4 + i) * LP + nt * 16 + frow] = accb[nt][i];
  __syncthreads();

#pragma unroll
  for (int r = 0; r < 4; ++r) {
    const int br = b0 + tb + 16 * r;
#pragma unroll
    for (int c = 0; c < 4; ++c) {
      const int oc = o0 + to + 16 * c;
      float res = acc[r][c].x + acc[r][c].y
                + lout[(tb + 16 * r) * LP + to + 16 * c];
      if (use_ws) {
        partial[(size_t)ks * BO + (size_t)br * OUT_F + oc] = res;
      } else {
        if (ks == 0) res += bias[oc];
        atomicAdd(out + (size_t)br * OUT_F + oc, res);
      }
    }
  }
}

__global__ __launch_bounds__(256)
void wkan_reduce(const float* __restrict__ partial, const float* __restrict__ bias,
                 float* __restrict__ out)
{
  const int i4 = (blockIdx.x * 256 + threadIdx.x) * 4;
  float4 r = *(const float4*)(bias + (i4 & (OUT_F - 1)));
#pragma unroll
  for (int k = 0; k < KS; ++k) {
    float4 a = *(const float4*)(partial + (size_t)k * BO + i4);
    r.x += a.x; r.y += a.y; r.z += a.z; r.w += a.w;
  }
  *(float4*)(out + i4) = r;
}

extern "C" void kernel_launch(void* const* d_in, const int* in_sizes, int n_in,
                              void* d_out, int out_size, void* d_ws, size_t ws_size,
                              hipStream_t stream) {
  const float* x  = (const float*)d_in[0];
  const float* bw = (const float*)d_in[1];
  const float* ww = (const float*)d_in[2];
  const float* sc = (const float*)d_in[3];
  const float* tr = (const float*)d_in[4];
  const float* bi = (const float*)d_in[5];
  float* out = (float*)d_out;

  const int use_ws = ws_size >= (size_t)KS * BO * sizeof(float) ? 1 : 0;
  if (!use_ws) {
    hipMemsetAsync(d_out, 0, (size_t)out_size * sizeof(float), stream);
  }
  dim3 grid(BATCH / BT, OUT_F / OT, KS);  // 16 x 8 x 8 = 1024 blocks, 4/CU
  wkan_main<<<grid, dim3(256), 0, stream>>>(x, bw, ww, sc, tr, bi,
                                            (float*)d_ws, out, use_ws);
  if (use_ws) {
    wkan_reduce<<<dim3(BO / 1024), dim3(256), 0, stream>>>((const float*)d_ws, bi, out);
  }
}

// Round 5
// 112.193 us; speedup vs baseline: 1.1275x; 1.1275x over previous
//
#include <hip/hip_runtime.h>

// out[b,o] = sum_i silu(x)*BW + ((xs^2-1)*exp(-xs^2/2))*WW + bias,  xs=(x-T)/S
// ROUND 11: R10 minus the T14 cross-chunk prefetch.  R10 post-mortem: FETCH
// 17.5->60MB, WRITE 16.4->83MB, VGPR_Count 64 == spill signature.  The
// launch_bounds(256,4) VGPR cap (128) cannot hold 20 live prefetch regs on
// top of acc(32)+accb(16)+transients -> compiler spilled to scratch; the
// +42/+66MB matches 20regs x 256thr x 1024blk x 3chunks.  R8 measured the
// prefetch's value at only ~1us; at 4 waves/SIMD TLP hides staging latency
// without it.  Keep: BT=64 tile, MFMA base branch (R9), aliased lout +
// 30720B LDS, grid 16x8x8 = 4 blocks/CU (R10).
// Wavelet math verified since round 2:
//   a2 = C2/s^2, m1 = -2*a2*t, m2' = a2*t^2 - C2, q = w * 2^C2 / C2
//   p = a2*x^2 + m1*x + m2';  contribution = p * q * 2^p,  C2 = -0.5*log2(e)

constexpr int IN_F  = 512;
constexpr int OUT_F = 512;
constexpr int BATCH = 1024;
constexpr int BT = 64, OT = 64;     // block tile
constexpr int KS = 8;               // k-split -> grid 16x8x8 = 1024 blocks
constexpr int KR = IN_F / KS;       // 64 k per block
constexpr int IT = 16;              // k chunk in LDS
constexpr int PITCH = IT + 4;       // f32 rows: 16B-aligned, 2-way banks (free)
constexpr int HP = IT + 4;          // f16 rows: 40B stride, conflict-free b64
constexpr int LP = OT + 1;          // epilogue merge pitch
constexpr int NCH = KR / IT;        // 4 chunks
constexpr int BO  = BATCH * OUT_F;  // 524288

#define LOG2E 1.44269504088897f
#define C2f   (-0.72134752044448f)
#define NC2f  ( 0.72134752044448f)
#define RQf   (-0.84083003f)   /* 2^C2 / C2 = e^{-1/2}/C2 */

typedef float v2f   __attribute__((ext_vector_type(2)));
typedef float f32x4 __attribute__((ext_vector_type(4)));
typedef _Float16 half4 __attribute__((ext_vector_type(4)));

__device__ __forceinline__ float fexp2(float v) { return __builtin_amdgcn_exp2f(v); }
__device__ __forceinline__ float frcp(float v)  { return __builtin_amdgcn_rcpf(v); }
__device__ __forceinline__ v2f pkfma(v2f a, v2f b, v2f c) {
  return __builtin_elementwise_fma(a, b, c);
}
__device__ __forceinline__ float fsilu(float v) {
  return v * frcp(1.f + fexp2(v * -LOG2E));
}

// LDS carve (floats):
//   lx   [   0..1279]  x tile, f32, 64x20
//   la   [1280..2559]  lm [2560..3839]  ln [3840..5119]  lq [5120..6399]
//   hx   [6400..7039]  silu(x) f16 64x20 (MFMA A)
//   hb   [7040..7679]  basew   f16 64x20 (MFMA B)
//   lout [   0..4159]  ALIAS of lx/la/lm/ln: epilogue merge 64x65 (after barrier)
constexpr int SMEM_F = 7680;        // 30720 B

__global__ __launch_bounds__(256, 4)
void wkan_main(const float* __restrict__ x, const float* __restrict__ basew,
               const float* __restrict__ wavew, const float* __restrict__ scale,
               const float* __restrict__ transl, const float* __restrict__ bias,
               float* __restrict__ partial, float* __restrict__ out, int use_ws)
{
  __shared__ float smem[SMEM_F];
  float* lx = smem;
  float* la = smem + 1280;
  float* lm = smem + 2560;
  float* ln = smem + 3840;
  float* lq = smem + 5120;
  _Float16* hx = (_Float16*)(smem + 6400);
  _Float16* hb = (_Float16*)(smem + 7040);
  float* lout = smem;               // epilogue alias

  const int tid = threadIdx.x;
  const int b0 = blockIdx.x * BT;
  const int o0 = blockIdx.y * OT;
  const int ks = blockIdx.z;
  const int k0 = ks * KR;

  const int srow = tid >> 2;        // 0..63 staging row
  const int sc4  = (tid & 3) * 4;   // 0,4,8,12
  const int lofs = srow * PITCH + sc4;
  const int hofs = srow * HP + sc4;

  const int to = tid & 15;          // output col group (cols to + 16c)
  const int tb = tid >> 4;          // output row group 0..15 (rows tb + 16r)

  const int lane = tid & 63;
  const int wid  = tid >> 6;        // wave 0..3 -> m-tile rows wid*16..wid*16+15
  const int frow = lane & 15;       // m/n within MFMA tile
  const int kgrp = (lane >> 4) * 4; // k group within chunk

  v2f zz; zz.x = 0.f; zz.y = 0.f;
  v2f acc[4][4];
#pragma unroll
  for (int r = 0; r < 4; ++r)
#pragma unroll
    for (int c = 0; c < 4; ++c) acc[r][c] = zz;

  f32x4 accb[4];                    // base-GEMM fragments: 4 n-tiles
#pragma unroll
  for (int nt = 0; nt < 4; ++nt) accb[nt] = (f32x4)0.f;

  for (int kc = 0; kc < NCH; ++kc) {
    const int g = k0 + kc * IT + sc4;
    if (kc) __syncthreads();          // prev-chunk readers done
    // ---------- stage chunk (direct loads; TLP hides latency at 4 blk/CU) --
    {
      float4 xv = *(const float4*)(x + (size_t)(b0 + srow) * IN_F + g);
      float4 sx;
      sx.x = fsilu(xv.x); sx.y = fsilu(xv.y); sx.z = fsilu(xv.z); sx.w = fsilu(xv.w);
      *(float4*)(lx + lofs) = xv;
      half4 h0;
      h0[0] = (_Float16)sx.x; h0[1] = (_Float16)sx.y;
      h0[2] = (_Float16)sx.z; h0[3] = (_Float16)sx.w;
      *(half4*)(hx + hofs) = h0;

      float4 sv = *(const float4*)(scale  + (size_t)(o0 + srow) * IN_F + g);
      float4 tv = *(const float4*)(transl + (size_t)(o0 + srow) * IN_F + g);
      float4 av, mv, nv;
      {
        float a2, a2t;
        a2 = C2f * frcp(sv.x * sv.x); a2t = a2 * tv.x;
        av.x = a2; mv.x = -2.f * a2t; nv.x = fmaf(a2t, tv.x, NC2f);
        a2 = C2f * frcp(sv.y * sv.y); a2t = a2 * tv.y;
        av.y = a2; mv.y = -2.f * a2t; nv.y = fmaf(a2t, tv.y, NC2f);
        a2 = C2f * frcp(sv.z * sv.z); a2t = a2 * tv.z;
        av.z = a2; mv.z = -2.f * a2t; nv.z = fmaf(a2t, tv.z, NC2f);
        a2 = C2f * frcp(sv.w * sv.w); a2t = a2 * tv.w;
        av.w = a2; mv.w = -2.f * a2t; nv.w = fmaf(a2t, tv.w, NC2f);
      }
      *(float4*)(la + lofs) = av;
      *(float4*)(lm + lofs) = mv;
      *(float4*)(ln + lofs) = nv;

      float4 wv = *(const float4*)(wavew + (size_t)(o0 + srow) * IN_F + g);
      float4 qv;
      qv.x = wv.x * RQf; qv.y = wv.y * RQf; qv.z = wv.z * RQf; qv.w = wv.w * RQf;
      *(float4*)(lq + lofs) = qv;

      float4 bv = *(const float4*)(basew + (size_t)(o0 + srow) * IN_F + g);
      half4 hbv;
      hbv[0] = (_Float16)bv.x; hbv[1] = (_Float16)bv.y;
      hbv[2] = (_Float16)bv.z; hbv[3] = (_Float16)bv.w;
      *(half4*)(hb + hofs) = hbv;
    }
    __syncthreads();                  // chunk kc ready in LDS

    // ---------- base branch: 4 MFMA on the matrix pipe ----------
    {
      half4 af = *(const half4*)(hx + (wid * 16 + frow) * HP + kgrp);
#pragma unroll
      for (int nt = 0; nt < 4; ++nt) {
        half4 bf = *(const half4*)(hb + (nt * 16 + frow) * HP + kgrp);
        accb[nt] = __builtin_amdgcn_mfma_f32_16x16x16f16(af, bf, accb[nt], 0, 0, 0);
      }
    }

    // ---------- wavelet: 4x4 outputs/thread on the VALU ----------
    for (int ii = 0; ii < IT; ii += 4) {
      float4 xr[4], x2[4];
#pragma unroll
      for (int r = 0; r < 4; ++r) {
        const int row = (tb + 16 * r) * PITCH + ii;
        xr[r] = *(const float4*)(lx + row);
        x2[r].x = xr[r].x * xr[r].x;
        x2[r].y = xr[r].y * xr[r].y;
        x2[r].z = xr[r].z * xr[r].z;
        x2[r].w = xr[r].w * xr[r].w;
      }
#pragma unroll
      for (int c = 0; c < 4; ++c) {
        const int orow = (to + 16 * c) * PITCH + ii;
        float4 A = *(const float4*)(la + orow);
        float4 M = *(const float4*)(lm + orow);
        float4 N = *(const float4*)(ln + orow);
        float4 Q = *(const float4*)(lq + orow);
        v2f Al = {A.x, A.y}, Ah = {A.z, A.w};
        v2f Ml = {M.x, M.y}, Mh = {M.z, M.w};
        v2f Nl = {N.x, N.y}, Nh = {N.z, N.w};
        v2f Ql = {Q.x, Q.y}, Qh = {Q.z, Q.w};
#pragma unroll
        for (int r = 0; r < 4; ++r) {
          v2f xl  = {xr[r].x, xr[r].y}, xh  = {xr[r].z, xr[r].w};
          v2f x2l = {x2[r].x, x2[r].y}, x2h = {x2[r].z, x2[r].w};
          v2f p, e, gg;
          p = pkfma(Al, x2l, pkfma(Ml, xl, Nl));
          e.x = fexp2(p.x); e.y = fexp2(p.y);
          gg = p * Ql;
          acc[r][c] = pkfma(gg, e, acc[r][c]);
          p = pkfma(Ah, x2h, pkfma(Mh, xh, Nh));
          e.x = fexp2(p.x); e.y = fexp2(p.y);
          gg = p * Qh;
          acc[r][c] = pkfma(gg, e, acc[r][c]);
        }
      }
    }
  }

  // ---------- epilogue: merge base fragments with wavelet acc ----------
  __syncthreads();                  // all LDS tile reads done; lout may alias
  // D layout: n = lane&15, m = (lane>>4)*4 + i   (within each 16x16 tile)
#pragma unroll
  for (int nt = 0; nt < 4; ++nt)
#pragma unroll
    for (int i = 0; i < 4; ++i)
      lout[(wid * 16 + (lane >> 4) * 4 + i) * LP + nt * 16 + frow] = accb[nt][i];
  __syncthreads();

#pragma unroll
  for (int r = 0; r < 4; ++r) {
    const int br = b0 + tb + 16 * r;
#pragma unroll
    for (int c = 0; c < 4; ++c) {
      const int oc = o0 + to + 16 * c;
      float res = acc[r][c].x + acc[r][c].y
                + lout[(tb + 16 * r) * LP + to + 16 * c];
      if (use_ws) {
        partial[(size_t)ks * BO + (size_t)br * OUT_F + oc] = res;
      } else {
        if (ks == 0) res += bias[oc];
        atomicAdd(out + (size_t)br * OUT_F + oc, res);
      }
    }
  }
}

__global__ __launch_bounds__(256)
void wkan_reduce(const float* __restrict__ partial, const float* __restrict__ bias,
                 float* __restrict__ out)
{
  const int i4 = (blockIdx.x * 256 + threadIdx.x) * 4;
  float4 r = *(const float4*)(bias + (i4 & (OUT_F - 1)));
#pragma unroll
  for (int k = 0; k < KS; ++k) {
    float4 a = *(const float4*)(partial + (size_t)k * BO + i4);
    r.x += a.x; r.y += a.y; r.z += a.z; r.w += a.w;
  }
  *(float4*)(out + i4) = r;
}

extern "C" void kernel_launch(void* const* d_in, const int* in_sizes, int n_in,
                              void* d_out, int out_size, void* d_ws, size_t ws_size,
                              hipStream_t stream) {
  const float* x  = (const float*)d_in[0];
  const float* bw = (const float*)d_in[1];
  const float* ww = (const float*)d_in[2];
  const float* sc = (const float*)d_in[3];
  const float* tr = (const float*)d_in[4];
  const float* bi = (const float*)d_in[5];
  float* out = (float*)d_out;

  const int use_ws = ws_size >= (size_t)KS * BO * sizeof(float) ? 1 : 0;
  if (!use_ws) {
    hipMemsetAsync(d_out, 0, (size_t)out_size * sizeof(float), stream);
  }
  dim3 grid(BATCH / BT, OUT_F / OT, KS);  // 16 x 8 x 8 = 1024 blocks, 4/CU
  wkan_main<<<grid, dim3(256), 0, stream>>>(x, bw, ww, sc, tr, bi,
                                            (float*)d_ws, out, use_ws);
  if (use_ws) {
    wkan_reduce<<<dim3(BO / 1024), dim3(256), 0, stream>>>((const float*)d_ws, bi, out);
  }
}

// Round 6
// 109.551 us; speedup vs baseline: 1.1547x; 1.0241x over previous
//
#include <hip/hip_runtime.h>

// out[b,o] = sum_i silu(x)*BW + ((xs^2-1)*exp(-xs^2/2))*WW + bias,  xs=(x-T)/S
// ROUND 12: R11 + amdgpu_waves_per_eu(4,4).  R11 post-mortem: VGPR_Count
// still 64 with launch_bounds(256,4); WRITE was +8192KB exactly over the
// R6 baseline (= ~8 spilled regs x 4B x 256thr x 1024blk) and FETCH +4.3MB.
// The allocator chased the 64-VGPR/8-wave occupancy step (launch_bounds's
// 2nd arg is only a MINIMUM waves/EU) and paid in scratch; spill stalls
// capped VALUBusy at 50%.  min=max=4 pins the target: cap 128 VGPR, no
// incentive to shrink to 64.  Estimated true pressure ~100-115 -> no spill.
// Everything else identical to R11: BT=64 tile, MFMA base branch (R9),
// aliased lout, 30720B LDS, grid 16x8x8 = 4 blocks/CU.
// Wavelet math verified since round 2:
//   a2 = C2/s^2, m1 = -2*a2*t, m2' = a2*t^2 - C2, q = w * 2^C2 / C2
//   p = a2*x^2 + m1*x + m2';  contribution = p * q * 2^p,  C2 = -0.5*log2(e)

constexpr int IN_F  = 512;
constexpr int OUT_F = 512;
constexpr int BATCH = 1024;
constexpr int BT = 64, OT = 64;     // block tile
constexpr int KS = 8;               // k-split -> grid 16x8x8 = 1024 blocks
constexpr int KR = IN_F / KS;       // 64 k per block
constexpr int IT = 16;              // k chunk in LDS
constexpr int PITCH = IT + 4;       // f32 rows: 16B-aligned, 2-way banks (free)
constexpr int HP = IT + 4;          // f16 rows: 40B stride, conflict-free b64
constexpr int LP = OT + 1;          // epilogue merge pitch
constexpr int NCH = KR / IT;        // 4 chunks
constexpr int BO  = BATCH * OUT_F;  // 524288

#define LOG2E 1.44269504088897f
#define C2f   (-0.72134752044448f)
#define NC2f  ( 0.72134752044448f)
#define RQf   (-0.84083003f)   /* 2^C2 / C2 = e^{-1/2}/C2 */

typedef float v2f   __attribute__((ext_vector_type(2)));
typedef float f32x4 __attribute__((ext_vector_type(4)));
typedef _Float16 half4 __attribute__((ext_vector_type(4)));

__device__ __forceinline__ float fexp2(float v) { return __builtin_amdgcn_exp2f(v); }
__device__ __forceinline__ float frcp(float v)  { return __builtin_amdgcn_rcpf(v); }
__device__ __forceinline__ v2f pkfma(v2f a, v2f b, v2f c) {
  return __builtin_elementwise_fma(a, b, c);
}
__device__ __forceinline__ float fsilu(float v) {
  return v * frcp(1.f + fexp2(v * -LOG2E));
}

// LDS carve (floats):
//   lx   [   0..1279]  x tile, f32, 64x20
//   la   [1280..2559]  lm [2560..3839]  ln [3840..5119]  lq [5120..6399]
//   hx   [6400..7039]  silu(x) f16 64x20 (MFMA A)
//   hb   [7040..7679]  basew   f16 64x20 (MFMA B)
//   lout [   0..4159]  ALIAS of lx/la/lm/ln: epilogue merge 64x65 (after barrier)
constexpr int SMEM_F = 7680;        // 30720 B

__global__ __launch_bounds__(256)
__attribute__((amdgpu_waves_per_eu(4, 4)))
void wkan_main(const float* __restrict__ x, const float* __restrict__ basew,
               const float* __restrict__ wavew, const float* __restrict__ scale,
               const float* __restrict__ transl, const float* __restrict__ bias,
               float* __restrict__ partial, float* __restrict__ out, int use_ws)
{
  __shared__ float smem[SMEM_F];
  float* lx = smem;
  float* la = smem + 1280;
  float* lm = smem + 2560;
  float* ln = smem + 3840;
  float* lq = smem + 5120;
  _Float16* hx = (_Float16*)(smem + 6400);
  _Float16* hb = (_Float16*)(smem + 7040);
  float* lout = smem;               // epilogue alias

  const int tid = threadIdx.x;
  const int b0 = blockIdx.x * BT;
  const int o0 = blockIdx.y * OT;
  const int ks = blockIdx.z;
  const int k0 = ks * KR;

  const int srow = tid >> 2;        // 0..63 staging row
  const int sc4  = (tid & 3) * 4;   // 0,4,8,12
  const int lofs = srow * PITCH + sc4;
  const int hofs = srow * HP + sc4;

  const int to = tid & 15;          // output col group (cols to + 16c)
  const int tb = tid >> 4;          // output row group 0..15 (rows tb + 16r)

  const int lane = tid & 63;
  const int wid  = tid >> 6;        // wave 0..3 -> m-tile rows wid*16..wid*16+15
  const int frow = lane & 15;       // m/n within MFMA tile
  const int kgrp = (lane >> 4) * 4; // k group within chunk

  v2f zz; zz.x = 0.f; zz.y = 0.f;
  v2f acc[4][4];
#pragma unroll
  for (int r = 0; r < 4; ++r)
#pragma unroll
    for (int c = 0; c < 4; ++c) acc[r][c] = zz;

  f32x4 accb[4];                    // base-GEMM fragments: 4 n-tiles
#pragma unroll
  for (int nt = 0; nt < 4; ++nt) accb[nt] = (f32x4)0.f;

  for (int kc = 0; kc < NCH; ++kc) {
    const int g = k0 + kc * IT + sc4;
    if (kc) __syncthreads();          // prev-chunk readers done
    // ---------- stage chunk (direct loads; TLP hides latency at 4 blk/CU) --
    {
      float4 xv = *(const float4*)(x + (size_t)(b0 + srow) * IN_F + g);
      float4 sx;
      sx.x = fsilu(xv.x); sx.y = fsilu(xv.y); sx.z = fsilu(xv.z); sx.w = fsilu(xv.w);
      *(float4*)(lx + lofs) = xv;
      half4 h0;
      h0[0] = (_Float16)sx.x; h0[1] = (_Float16)sx.y;
      h0[2] = (_Float16)sx.z; h0[3] = (_Float16)sx.w;
      *(half4*)(hx + hofs) = h0;

      float4 sv = *(const float4*)(scale  + (size_t)(o0 + srow) * IN_F + g);
      float4 tv = *(const float4*)(transl + (size_t)(o0 + srow) * IN_F + g);
      float4 av, mv, nv;
      {
        float a2, a2t;
        a2 = C2f * frcp(sv.x * sv.x); a2t = a2 * tv.x;
        av.x = a2; mv.x = -2.f * a2t; nv.x = fmaf(a2t, tv.x, NC2f);
        a2 = C2f * frcp(sv.y * sv.y); a2t = a2 * tv.y;
        av.y = a2; mv.y = -2.f * a2t; nv.y = fmaf(a2t, tv.y, NC2f);
        a2 = C2f * frcp(sv.z * sv.z); a2t = a2 * tv.z;
        av.z = a2; mv.z = -2.f * a2t; nv.z = fmaf(a2t, tv.z, NC2f);
        a2 = C2f * frcp(sv.w * sv.w); a2t = a2 * tv.w;
        av.w = a2; mv.w = -2.f * a2t; nv.w = fmaf(a2t, tv.w, NC2f);
      }
      *(float4*)(la + lofs) = av;
      *(float4*)(lm + lofs) = mv;
      *(float4*)(ln + lofs) = nv;

      float4 wv = *(const float4*)(wavew + (size_t)(o0 + srow) * IN_F + g);
      float4 qv;
      qv.x = wv.x * RQf; qv.y = wv.y * RQf; qv.z = wv.z * RQf; qv.w = wv.w * RQf;
      *(float4*)(lq + lofs) = qv;

      float4 bv = *(const float4*)(basew + (size_t)(o0 + srow) * IN_F + g);
      half4 hbv;
      hbv[0] = (_Float16)bv.x; hbv[1] = (_Float16)bv.y;
      hbv[2] = (_Float16)bv.z; hbv[3] = (_Float16)bv.w;
      *(half4*)(hb + hofs) = hbv;
    }
    __syncthreads();                  // chunk kc ready in LDS

    // ---------- base branch: 4 MFMA on the matrix pipe ----------
    {
      half4 af = *(const half4*)(hx + (wid * 16 + frow) * HP + kgrp);
#pragma unroll
      for (int nt = 0; nt < 4; ++nt) {
        half4 bf = *(const half4*)(hb + (nt * 16 + frow) * HP + kgrp);
        accb[nt] = __builtin_amdgcn_mfma_f32_16x16x16f16(af, bf, accb[nt], 0, 0, 0);
      }
    }

    // ---------- wavelet: 4x4 outputs/thread on the VALU ----------
    for (int ii = 0; ii < IT; ii += 4) {
      float4 xr[4], x2[4];
#pragma unroll
      for (int r = 0; r < 4; ++r) {
        const int row = (tb + 16 * r) * PITCH + ii;
        xr[r] = *(const float4*)(lx + row);
        x2[r].x = xr[r].x * xr[r].x;
        x2[r].y = xr[r].y * xr[r].y;
        x2[r].z = xr[r].z * xr[r].z;
        x2[r].w = xr[r].w * xr[r].w;
      }
#pragma unroll
      for (int c = 0; c < 4; ++c) {
        const int orow = (to + 16 * c) * PITCH + ii;
        float4 A = *(const float4*)(la + orow);
        float4 M = *(const float4*)(lm + orow);
        float4 N = *(const float4*)(ln + orow);
        float4 Q = *(const float4*)(lq + orow);
        v2f Al = {A.x, A.y}, Ah = {A.z, A.w};
        v2f Ml = {M.x, M.y}, Mh = {M.z, M.w};
        v2f Nl = {N.x, N.y}, Nh = {N.z, N.w};
        v2f Ql = {Q.x, Q.y}, Qh = {Q.z, Q.w};
#pragma unroll
        for (int r = 0; r < 4; ++r) {
          v2f xl  = {xr[r].x, xr[r].y}, xh  = {xr[r].z, xr[r].w};
          v2f x2l = {x2[r].x, x2[r].y}, x2h = {x2[r].z, x2[r].w};
          v2f p, e, gg;
          p = pkfma(Al, x2l, pkfma(Ml, xl, Nl));
          e.x = fexp2(p.x); e.y = fexp2(p.y);
          gg = p * Ql;
          acc[r][c] = pkfma(gg, e, acc[r][c]);
          p = pkfma(Ah, x2h, pkfma(Mh, xh, Nh));
          e.x = fexp2(p.x); e.y = fexp2(p.y);
          gg = p * Qh;
          acc[r][c] = pkfma(gg, e, acc[r][c]);
        }
      }
    }
  }

  // ---------- epilogue: merge base fragments with wavelet acc ----------
  __syncthreads();                  // all LDS tile reads done; lout may alias
  // D layout: n = lane&15, m = (lane>>4)*4 + i   (within each 16x16 tile)
#pragma unroll
  for (int nt = 0; nt < 4; ++nt)
#pragma unroll
    for (int i = 0; i < 4; ++i)
      lout[(wid * 16 + (lane >> 4) * 4 + i) * LP + nt * 16 + frow] = accb[nt][i];
  __syncthreads();

#pragma unroll
  for (int r = 0; r < 4; ++r) {
    const int br = b0 + tb + 16 * r;
#pragma unroll
    for (int c = 0; c < 4; ++c) {
      const int oc = o0 + to + 16 * c;
      float res = acc[r][c].x + acc[r][c].y
                + lout[(tb + 16 * r) * LP + to + 16 * c];
      if (use_ws) {
        partial[(size_t)ks * BO + (size_t)br * OUT_F + oc] = res;
      } else {
        if (ks == 0) res += bias[oc];
        atomicAdd(out + (size_t)br * OUT_F + oc, res);
      }
    }
  }
}

__global__ __launch_bounds__(256)
void wkan_reduce(const float* __restrict__ partial, const float* __restrict__ bias,
                 float* __restrict__ out)
{
  const int i4 = (blockIdx.x * 256 + threadIdx.x) * 4;
  float4 r = *(const float4*)(bias + (i4 & (OUT_F - 1)));
#pragma unroll
  for (int k = 0; k < KS; ++k) {
    float4 a = *(const float4*)(partial + (size_t)k * BO + i4);
    r.x += a.x; r.y += a.y; r.z += a.z; r.w += a.w;
  }
  *(float4*)(out + i4) = r;
}

extern "C" void kernel_launch(void* const* d_in, const int* in_sizes, int n_in,
                              void* d_out, int out_size, void* d_ws, size_t ws_size,
                              hipStream_t stream) {
  const float* x  = (const float*)d_in[0];
  const float* bw = (const float*)d_in[1];
  const float* ww = (const float*)d_in[2];
  const float* sc = (const float*)d_in[3];
  const float* tr = (const float*)d_in[4];
  const float* bi = (const float*)d_in[5];
  float* out = (float*)d_out;

  const int use_ws = ws_size >= (size_t)KS * BO * sizeof(float) ? 1 : 0;
  if (!use_ws) {
    hipMemsetAsync(d_out, 0, (size_t)out_size * sizeof(float), stream);
  }
  dim3 grid(BATCH / BT, OUT_F / OT, KS);  // 16 x 8 x 8 = 1024 blocks, 4/CU
  wkan_main<<<grid, dim3(256), 0, stream>>>(x, bw, ww, sc, tr, bi,
                                            (float*)d_ws, out, use_ws);
  if (use_ws) {
    wkan_reduce<<<dim3(BO / 1024), dim3(256), 0, stream>>>((const float*)d_ws, bi, out);
  }
}

// Round 7
// 108.934 us; speedup vs baseline: 1.1612x; 1.0057x over previous
//
#include <hip/hip_runtime.h>

// out[b,o] = sum_i silu(x)*BW + ((xs^2-1)*exp(-xs^2/2))*WW + bias,  xs=(x-T)/S
// ROUND 13: two register-pressure fixes on the R12 structure.
//  (1) Horner:  p = a2*x^2 + m1*x + m2'  ==  (a2*x + m1)*x + m2'
//      -> x2[] precompute deleted: -8 pk-muls/ii-step (~8% main VALU) and
//         -16 transient VGPRs.
//  (2) __launch_bounds__(256,2): the ONLY bound that empirically allocates
//      without spilling (R9: VGPR 120, WRITE exactly 16.4MB).  (256,4) and
//      waves_per_eu(4,4) both produced VGPR_Count=64 + scratch traffic
//      (R11: +8.2MB write, R12: +4.1MB) -- allocator chases the 8-wave step.
//      With LDS now 30720B (R10's aliased lout), <=128 VGPR gives
//      4 blocks/CU = 4 waves/SIMD -- the config never yet benched.
// Base branch on matrix pipe (v_mfma_f32_16x16x16f16, verified R9).
// Wavelet math verified since round 2:
//   a2 = C2/s^2, m1 = -2*a2*t, m2' = a2*t^2 - C2, q = w * 2^C2 / C2
//   p = (a2*x + m1)*x + m2';  contribution = p * q * 2^p,  C2 = -0.5*log2(e)

constexpr int IN_F  = 512;
constexpr int OUT_F = 512;
constexpr int BATCH = 1024;
constexpr int BT = 64, OT = 64;     // block tile
constexpr int KS = 8;               // k-split -> grid 16x8x8 = 1024 blocks
constexpr int KR = IN_F / KS;       // 64 k per block
constexpr int IT = 16;              // k chunk in LDS
constexpr int PITCH = IT + 4;       // f32 rows: 16B-aligned, 2-way banks (free)
constexpr int HP = IT + 4;          // f16 rows: 40B stride, conflict-free b64
constexpr int LP = OT + 1;          // epilogue merge pitch
constexpr int NCH = KR / IT;        // 4 chunks
constexpr int BO  = BATCH * OUT_F;  // 524288

#define LOG2E 1.44269504088897f
#define C2f   (-0.72134752044448f)
#define NC2f  ( 0.72134752044448f)
#define RQf   (-0.84083003f)   /* 2^C2 / C2 = e^{-1/2}/C2 */

typedef float v2f   __attribute__((ext_vector_type(2)));
typedef float f32x4 __attribute__((ext_vector_type(4)));
typedef _Float16 half4 __attribute__((ext_vector_type(4)));

__device__ __forceinline__ float fexp2(float v) { return __builtin_amdgcn_exp2f(v); }
__device__ __forceinline__ float frcp(float v)  { return __builtin_amdgcn_rcpf(v); }
__device__ __forceinline__ v2f pkfma(v2f a, v2f b, v2f c) {
  return __builtin_elementwise_fma(a, b, c);
}
__device__ __forceinline__ float fsilu(float v) {
  return v * frcp(1.f + fexp2(v * -LOG2E));
}

// LDS carve (floats):
//   lx   [   0..1279]  x tile, f32, 64x20
//   la   [1280..2559]  lm [2560..3839]  ln [3840..5119]  lq [5120..6399]
//   hx   [6400..7039]  silu(x) f16 64x20 (MFMA A)
//   hb   [7040..7679]  basew   f16 64x20 (MFMA B)
//   lout [   0..4159]  ALIAS of lx/la/lm/ln: epilogue merge 64x65 (after barrier)
constexpr int SMEM_F = 7680;        // 30720 B

__global__ __launch_bounds__(256, 2)
void wkan_main(const float* __restrict__ x, const float* __restrict__ basew,
               const float* __restrict__ wavew, const float* __restrict__ scale,
               const float* __restrict__ transl, const float* __restrict__ bias,
               float* __restrict__ partial, float* __restrict__ out, int use_ws)
{
  __shared__ float smem[SMEM_F];
  float* lx = smem;
  float* la = smem + 1280;
  float* lm = smem + 2560;
  float* ln = smem + 3840;
  float* lq = smem + 5120;
  _Float16* hx = (_Float16*)(smem + 6400);
  _Float16* hb = (_Float16*)(smem + 7040);
  float* lout = smem;               // epilogue alias

  const int tid = threadIdx.x;
  const int b0 = blockIdx.x * BT;
  const int o0 = blockIdx.y * OT;
  const int ks = blockIdx.z;
  const int k0 = ks * KR;

  const int srow = tid >> 2;        // 0..63 staging row
  const int sc4  = (tid & 3) * 4;   // 0,4,8,12
  const int lofs = srow * PITCH + sc4;
  const int hofs = srow * HP + sc4;

  const int to = tid & 15;          // output col group (cols to + 16c)
  const int tb = tid >> 4;          // output row group 0..15 (rows tb + 16r)

  const int lane = tid & 63;
  const int wid  = tid >> 6;        // wave 0..3 -> m-tile rows wid*16..wid*16+15
  const int frow = lane & 15;       // m/n within MFMA tile
  const int kgrp = (lane >> 4) * 4; // k group within chunk

  v2f zz; zz.x = 0.f; zz.y = 0.f;
  v2f acc[4][4];
#pragma unroll
  for (int r = 0; r < 4; ++r)
#pragma unroll
    for (int c = 0; c < 4; ++c) acc[r][c] = zz;

  f32x4 accb[4];                    // base-GEMM fragments: 4 n-tiles
#pragma unroll
  for (int nt = 0; nt < 4; ++nt) accb[nt] = (f32x4)0.f;

  for (int kc = 0; kc < NCH; ++kc) {
    const int g = k0 + kc * IT + sc4;
    if (kc) __syncthreads();          // prev-chunk readers done
    // ---------- stage chunk (direct loads; TLP hides latency at 4 blk/CU) --
    {
      float4 xv = *(const float4*)(x + (size_t)(b0 + srow) * IN_F + g);
      float4 sx;
      sx.x = fsilu(xv.x); sx.y = fsilu(xv.y); sx.z = fsilu(xv.z); sx.w = fsilu(xv.w);
      *(float4*)(lx + lofs) = xv;
      half4 h0;
      h0[0] = (_Float16)sx.x; h0[1] = (_Float16)sx.y;
      h0[2] = (_Float16)sx.z; h0[3] = (_Float16)sx.w;
      *(half4*)(hx + hofs) = h0;

      float4 sv = *(const float4*)(scale  + (size_t)(o0 + srow) * IN_F + g);
      float4 tv = *(const float4*)(transl + (size_t)(o0 + srow) * IN_F + g);
      float4 av, mv, nv;
      {
        float a2, a2t;
        a2 = C2f * frcp(sv.x * sv.x); a2t = a2 * tv.x;
        av.x = a2; mv.x = -2.f * a2t; nv.x = fmaf(a2t, tv.x, NC2f);
        a2 = C2f * frcp(sv.y * sv.y); a2t = a2 * tv.y;
        av.y = a2; mv.y = -2.f * a2t; nv.y = fmaf(a2t, tv.y, NC2f);
        a2 = C2f * frcp(sv.z * sv.z); a2t = a2 * tv.z;
        av.z = a2; mv.z = -2.f * a2t; nv.z = fmaf(a2t, tv.z, NC2f);
        a2 = C2f * frcp(sv.w * sv.w); a2t = a2 * tv.w;
        av.w = a2; mv.w = -2.f * a2t; nv.w = fmaf(a2t, tv.w, NC2f);
      }
      *(float4*)(la + lofs) = av;
      *(float4*)(lm + lofs) = mv;
      *(float4*)(ln + lofs) = nv;

      float4 wv = *(const float4*)(wavew + (size_t)(o0 + srow) * IN_F + g);
      float4 qv;
      qv.x = wv.x * RQf; qv.y = wv.y * RQf; qv.z = wv.z * RQf; qv.w = wv.w * RQf;
      *(float4*)(lq + lofs) = qv;

      float4 bv = *(const float4*)(basew + (size_t)(o0 + srow) * IN_F + g);
      half4 hbv;
      hbv[0] = (_Float16)bv.x; hbv[1] = (_Float16)bv.y;
      hbv[2] = (_Float16)bv.z; hbv[3] = (_Float16)bv.w;
      *(half4*)(hb + hofs) = hbv;
    }
    __syncthreads();                  // chunk kc ready in LDS

    // ---------- base branch: 4 MFMA on the matrix pipe ----------
    {
      half4 af = *(const half4*)(hx + (wid * 16 + frow) * HP + kgrp);
#pragma unroll
      for (int nt = 0; nt < 4; ++nt) {
        half4 bf = *(const half4*)(hb + (nt * 16 + frow) * HP + kgrp);
        accb[nt] = __builtin_amdgcn_mfma_f32_16x16x16f16(af, bf, accb[nt], 0, 0, 0);
      }
    }

    // ---------- wavelet: 4x4 outputs/thread on the VALU (Horner) ----------
    for (int ii = 0; ii < IT; ii += 4) {
      float4 xr[4];
#pragma unroll
      for (int r = 0; r < 4; ++r) {
        const int row = (tb + 16 * r) * PITCH + ii;
        xr[r] = *(const float4*)(lx + row);
      }
#pragma unroll
      for (int c = 0; c < 4; ++c) {
        const int orow = (to + 16 * c) * PITCH + ii;
        float4 A = *(const float4*)(la + orow);
        float4 M = *(const float4*)(lm + orow);
        float4 N = *(const float4*)(ln + orow);
        float4 Q = *(const float4*)(lq + orow);
        v2f Al = {A.x, A.y}, Ah = {A.z, A.w};
        v2f Ml = {M.x, M.y}, Mh = {M.z, M.w};
        v2f Nl = {N.x, N.y}, Nh = {N.z, N.w};
        v2f Ql = {Q.x, Q.y}, Qh = {Q.z, Q.w};
#pragma unroll
        for (int r = 0; r < 4; ++r) {
          v2f xl  = {xr[r].x, xr[r].y}, xh  = {xr[r].z, xr[r].w};
          v2f p, e, gg;
          p = pkfma(pkfma(Al, xl, Ml), xl, Nl);
          e.x = fexp2(p.x); e.y = fexp2(p.y);
          gg = p * Ql;
          acc[r][c] = pkfma(gg, e, acc[r][c]);
          p = pkfma(pkfma(Ah, xh, Mh), xh, Nh);
          e.x = fexp2(p.x); e.y = fexp2(p.y);
          gg = p * Qh;
          acc[r][c] = pkfma(gg, e, acc[r][c]);
        }
      }
    }
  }

  // ---------- epilogue: merge base fragments with wavelet acc ----------
  __syncthreads();                  // all LDS tile reads done; lout may alias
  // D layout: n = lane&15, m = (lane>>4)*4 + i   (within each 16x16 tile)
#pragma unroll
  for (int nt = 0; nt < 4; ++nt)
#pragma unroll
    for (int i = 0; i < 4; ++i)
      lout[(wid * 16 + (lane >> 4) * 4 + i) * LP + nt * 16 + frow] = accb[nt][i];
  __syncthreads();

#pragma unroll
  for (int r = 0; r < 4; ++r) {
    const int br = b0 + tb + 16 * r;
#pragma unroll
    for (int c = 0; c < 4; ++c) {
      const int oc = o0 + to + 16 * c;
      float res = acc[r][c].x + acc[r][c].y
                + lout[(tb + 16 * r) * LP + to + 16 * c];
      if (use_ws) {
        partial[(size_t)ks * BO + (size_t)br * OUT_F + oc] = res;
      } else {
        if (ks == 0) res += bias[oc];
        atomicAdd(out + (size_t)br * OUT_F + oc, res);
      }
    }
  }
}

__global__ __launch_bounds__(256)
void wkan_reduce(const float* __restrict__ partial, const float* __restrict__ bias,
                 float* __restrict__ out)
{
  const int i4 = (blockIdx.x * 256 + threadIdx.x) * 4;
  float4 r = *(const float4*)(bias + (i4 & (OUT_F - 1)));
#pragma unroll
  for (int k = 0; k < KS; ++k) {
    float4 a = *(const float4*)(partial + (size_t)k * BO + i4);
    r.x += a.x; r.y += a.y; r.z += a.z; r.w += a.w;
  }
  *(float4*)(out + i4) = r;
}

extern "C" void kernel_launch(void* const* d_in, const int* in_sizes, int n_in,
                              void* d_out, int out_size, void* d_ws, size_t ws_size,
                              hipStream_t stream) {
  const float* x  = (const float*)d_in[0];
  const float* bw = (const float*)d_in[1];
  const float* ww = (const float*)d_in[2];
  const float* sc = (const float*)d_in[3];
  const float* tr = (const float*)d_in[4];
  const float* bi = (const float*)d_in[5];
  float* out = (float*)d_out;

  const int use_ws = ws_size >= (size_t)KS * BO * sizeof(float) ? 1 : 0;
  if (!use_ws) {
    hipMemsetAsync(d_out, 0, (size_t)out_size * sizeof(float), stream);
  }
  dim3 grid(BATCH / BT, OUT_F / OT, KS);  // 16 x 8 x 8 = 1024 blocks, 4/CU
  wkan_main<<<grid, dim3(256), 0, stream>>>(x, bw, ww, sc, tr, bi,
                                            (float*)d_ws, out, use_ws);
  if (use_ws) {
    wkan_reduce<<<dim3(BO / 1024), dim3(256), 0, stream>>>((const float*)d_ws, bi, out);
  }
}

// Round 8
// 107.580 us; speedup vs baseline: 1.1758x; 1.0126x over previous
//
#include <hip/hip_runtime.h>

// out[b,o] = sum_i silu(x)*BW + ((xs^2-1)*exp(-xs^2/2))*WW + bias,  xs=(x-T)/S
// ROUND 14: retile 4x4 -> 8x2 (BT=128, OT=32), keeping grid=1024 (8x16x8)
// = 4 blocks/CU.  R13 post-mortem: VALU busy 29.4us == issue floor; the
// 19us idle gap correlates with LDS read-pipe occupancy: 20 ds_read_b128
// per ii-step (16 param + 4 x) per 64 contributions = 5 B/contribution ->
// 1.34GB ~= 21-26us of LDS pipe, nearly as big as VALU.  8x2 tile: 16 reads
// per 64 contributions = 4 B/contribution (-20%), params shrink (OT=32) ->
// LDS 26880B.  xr[8] adds ~16 live regs -> est. 96-112 VGPR under the
// empirically-generous (256,2) bound (R9: 120, no spill); <=128 keeps
// 4 waves/SIMD.  Falsifier: VGPR_Count=64 again => spill => abort path.
// Base branch on matrix pipe: wave wid owns m-tiles {2wid,2wid+1} x
// n-tiles {0,1} (accb[2][2]).  Wavelet math verified since round 2:
//   a2 = C2/s^2, m1 = -2*a2*t, m2' = a2*t^2 - C2, q = w * 2^C2 / C2
//   p = (a2*x + m1)*x + m2';  contribution = p * q * 2^p,  C2 = -0.5*log2(e)

constexpr int IN_F  = 512;
constexpr int OUT_F = 512;
constexpr int BATCH = 1024;
constexpr int BT = 128, OT = 32;    // block tile (8x2 per thread)
constexpr int KS = 8;               // k-split -> grid 8x16x8 = 1024 blocks
constexpr int KR = IN_F / KS;       // 64 k per block
constexpr int IT = 16;              // k chunk in LDS
constexpr int PITCH = IT + 4;       // f32 rows: 16B-aligned, 2-way banks (free)
constexpr int HP = IT + 4;          // f16 rows: 40B stride, conflict-free b64
constexpr int LP = OT + 1;          // epilogue merge pitch (128 x 33)
constexpr int NCH = KR / IT;        // 4 chunks
constexpr int BO  = BATCH * OUT_F;  // 524288

#define LOG2E 1.44269504088897f
#define C2f   (-0.72134752044448f)
#define NC2f  ( 0.72134752044448f)
#define RQf   (-0.84083003f)   /* 2^C2 / C2 = e^{-1/2}/C2 */

typedef float v2f   __attribute__((ext_vector_type(2)));
typedef float f32x4 __attribute__((ext_vector_type(4)));
typedef _Float16 half4 __attribute__((ext_vector_type(4)));

__device__ __forceinline__ float fexp2(float v) { return __builtin_amdgcn_exp2f(v); }
__device__ __forceinline__ float frcp(float v)  { return __builtin_amdgcn_rcpf(v); }
__device__ __forceinline__ v2f pkfma(v2f a, v2f b, v2f c) {
  return __builtin_elementwise_fma(a, b, c);
}
__device__ __forceinline__ float fsilu(float v) {
  return v * frcp(1.f + fexp2(v * -LOG2E));
}

// LDS carve (float offsets):
//   lx   [    0..2559]  x tile f32, 128x20
//   la   [ 2560..3199]  lm [3200..3839]  ln [3840..4479]  lq [4480..5119]  (32x20)
//   hx   [ 5120..6399]  silu(x) f16 128x20 (MFMA A)
//   hb   [ 6400..6719]  basew   f16  32x20 (MFMA B)
//   lout [    0..4223]  ALIAS: epilogue merge 128x33 (after barrier)
constexpr int SMEM_F = 6720;        // 26880 B -> 4 blocks/CU (grid-capped)

__global__ __launch_bounds__(256, 2)
void wkan_main(const float* __restrict__ x, const float* __restrict__ basew,
               const float* __restrict__ wavew, const float* __restrict__ scale,
               const float* __restrict__ transl, const float* __restrict__ bias,
               float* __restrict__ partial, float* __restrict__ out, int use_ws)
{
  __shared__ float smem[SMEM_F];
  float* lx = smem;
  float* la = smem + 2560;
  float* lm = smem + 3200;
  float* ln = smem + 3840;
  float* lq = smem + 4480;
  _Float16* hx = (_Float16*)(smem + 5120);
  _Float16* hb = (_Float16*)(smem + 6400);
  float* lout = smem;               // epilogue alias

  const int tid = threadIdx.x;
  const int b0 = blockIdx.x * BT;
  const int o0 = blockIdx.y * OT;
  const int ks = blockIdx.z;
  const int k0 = ks * KR;

  const int srow = tid >> 2;        // 0..63: x rows srow and srow+64
  const int sc4  = (tid & 3) * 4;   // 0,4,8,12
  const int lofs = srow * PITCH + sc4;
  const int hofs = srow * HP + sc4;
  const int prow = tid >> 2;        // 0..31 valid when tid<128 (param rows)
  const int pofs = prow * PITCH + sc4;

  const int to = tid & 15;          // output col group (cols to + 16c, c<2)
  const int tb = tid >> 4;          // output row group 0..15 (rows tb + 16r, r<8)

  const int lane = tid & 63;
  const int wid  = tid >> 6;        // wave 0..3 -> m-tiles 2wid, 2wid+1
  const int frow = lane & 15;       // m/n within MFMA tile
  const int kgrp = (lane >> 4) * 4; // k group within chunk

  v2f zz; zz.x = 0.f; zz.y = 0.f;
  v2f acc[8][2];
#pragma unroll
  for (int r = 0; r < 8; ++r)
#pragma unroll
    for (int c = 0; c < 2; ++c) acc[r][c] = zz;

  f32x4 accb[2][2];                 // base-GEMM fragments: 2 m-tiles x 2 n-tiles
#pragma unroll
  for (int mt = 0; mt < 2; ++mt)
#pragma unroll
    for (int nt = 0; nt < 2; ++nt) accb[mt][nt] = (f32x4)0.f;

  for (int kc = 0; kc < NCH; ++kc) {
    const int g = k0 + kc * IT + sc4;
    if (kc) __syncthreads();          // prev-chunk readers done
    // ---------- stage chunk ----------
    {
      // x: 128 rows, every thread stages rows srow and srow+64
      float4 xv0 = *(const float4*)(x + (size_t)(b0 + srow)      * IN_F + g);
      float4 xv1 = *(const float4*)(x + (size_t)(b0 + srow + 64) * IN_F + g);
      float4 sx0, sx1;
      sx0.x = fsilu(xv0.x); sx0.y = fsilu(xv0.y); sx0.z = fsilu(xv0.z); sx0.w = fsilu(xv0.w);
      sx1.x = fsilu(xv1.x); sx1.y = fsilu(xv1.y); sx1.z = fsilu(xv1.z); sx1.w = fsilu(xv1.w);
      *(float4*)(lx + lofs) = xv0;
      *(float4*)(lx + lofs + 64 * PITCH) = xv1;
      half4 h0, h1;
      h0[0] = (_Float16)sx0.x; h0[1] = (_Float16)sx0.y;
      h0[2] = (_Float16)sx0.z; h0[3] = (_Float16)sx0.w;
      h1[0] = (_Float16)sx1.x; h1[1] = (_Float16)sx1.y;
      h1[2] = (_Float16)sx1.z; h1[3] = (_Float16)sx1.w;
      *(half4*)(hx + hofs) = h0;
      *(half4*)(hx + hofs + 64 * HP) = h1;

      // params: 32 rows, staged by threads 0..127
      if (tid < 128) {
        float4 sv = *(const float4*)(scale  + (size_t)(o0 + prow) * IN_F + g);
        float4 tv = *(const float4*)(transl + (size_t)(o0 + prow) * IN_F + g);
        float4 av, mv, nv;
        {
          float a2, a2t;
          a2 = C2f * frcp(sv.x * sv.x); a2t = a2 * tv.x;
          av.x = a2; mv.x = -2.f * a2t; nv.x = fmaf(a2t, tv.x, NC2f);
          a2 = C2f * frcp(sv.y * sv.y); a2t = a2 * tv.y;
          av.y = a2; mv.y = -2.f * a2t; nv.y = fmaf(a2t, tv.y, NC2f);
          a2 = C2f * frcp(sv.z * sv.z); a2t = a2 * tv.z;
          av.z = a2; mv.z = -2.f * a2t; nv.z = fmaf(a2t, tv.z, NC2f);
          a2 = C2f * frcp(sv.w * sv.w); a2t = a2 * tv.w;
          av.w = a2; mv.w = -2.f * a2t; nv.w = fmaf(a2t, tv.w, NC2f);
        }
        *(float4*)(la + pofs) = av;
        *(float4*)(lm + pofs) = mv;
        *(float4*)(ln + pofs) = nv;

        float4 wv = *(const float4*)(wavew + (size_t)(o0 + prow) * IN_F + g);
        float4 qv;
        qv.x = wv.x * RQf; qv.y = wv.y * RQf; qv.z = wv.z * RQf; qv.w = wv.w * RQf;
        *(float4*)(lq + pofs) = qv;

        float4 bv = *(const float4*)(basew + (size_t)(o0 + prow) * IN_F + g);
        half4 hbv;
        hbv[0] = (_Float16)bv.x; hbv[1] = (_Float16)bv.y;
        hbv[2] = (_Float16)bv.z; hbv[3] = (_Float16)bv.w;
        *(half4*)(hb + pofs) = hbv;
      }
    }
    __syncthreads();                  // chunk kc ready in LDS

    // ---------- base branch: 4 MFMA on the matrix pipe ----------
    {
      half4 af0 = *(const half4*)(hx + (wid * 32 +      frow) * HP + kgrp);
      half4 af1 = *(const half4*)(hx + (wid * 32 + 16 + frow) * HP + kgrp);
      half4 bf0 = *(const half4*)(hb + (       frow) * HP + kgrp);
      half4 bf1 = *(const half4*)(hb + (16 +   frow) * HP + kgrp);
      accb[0][0] = __builtin_amdgcn_mfma_f32_16x16x16f16(af0, bf0, accb[0][0], 0, 0, 0);
      accb[0][1] = __builtin_amdgcn_mfma_f32_16x16x16f16(af0, bf1, accb[0][1], 0, 0, 0);
      accb[1][0] = __builtin_amdgcn_mfma_f32_16x16x16f16(af1, bf0, accb[1][0], 0, 0, 0);
      accb[1][1] = __builtin_amdgcn_mfma_f32_16x16x16f16(af1, bf1, accb[1][1], 0, 0, 0);
    }

    // ---------- wavelet: 8x2 outputs/thread on the VALU (Horner) ----------
    for (int ii = 0; ii < IT; ii += 4) {
      float4 xr[8];
#pragma unroll
      for (int r = 0; r < 8; ++r) {
        const int row = (tb + 16 * r) * PITCH + ii;
        xr[r] = *(const float4*)(lx + row);
      }
#pragma unroll
      for (int c = 0; c < 2; ++c) {
        const int orow = (to + 16 * c) * PITCH + ii;
        float4 A = *(const float4*)(la + orow);
        float4 M = *(const float4*)(lm + orow);
        float4 N = *(const float4*)(ln + orow);
        float4 Q = *(const float4*)(lq + orow);
        v2f Al = {A.x, A.y}, Ah = {A.z, A.w};
        v2f Ml = {M.x, M.y}, Mh = {M.z, M.w};
        v2f Nl = {N.x, N.y}, Nh = {N.z, N.w};
        v2f Ql = {Q.x, Q.y}, Qh = {Q.z, Q.w};
#pragma unroll
        for (int r = 0; r < 8; ++r) {
          v2f xl  = {xr[r].x, xr[r].y}, xh  = {xr[r].z, xr[r].w};
          v2f p, e, gg;
          p = pkfma(pkfma(Al, xl, Ml), xl, Nl);
          e.x = fexp2(p.x); e.y = fexp2(p.y);
          gg = p * Ql;
          acc[r][c] = pkfma(gg, e, acc[r][c]);
          p = pkfma(pkfma(Ah, xh, Mh), xh, Nh);
          e.x = fexp2(p.x); e.y = fexp2(p.y);
          gg = p * Qh;
          acc[r][c] = pkfma(gg, e, acc[r][c]);
        }
      }
    }
  }

  // ---------- epilogue: merge base fragments with wavelet acc ----------
  __syncthreads();                  // all LDS tile reads done; lout may alias
  // D layout: n = lane&15, m = (lane>>4)*4 + i   (within each 16x16 tile)
#pragma unroll
  for (int mt = 0; mt < 2; ++mt)
#pragma unroll
    for (int nt = 0; nt < 2; ++nt)
#pragma unroll
      for (int i = 0; i < 4; ++i)
        lout[(wid * 32 + mt * 16 + (lane >> 4) * 4 + i) * LP + nt * 16 + frow]
            = accb[mt][nt][i];
  __syncthreads();

#pragma unroll
  for (int r = 0; r < 8; ++r) {
    const int br = b0 + tb + 16 * r;
#pragma unroll
    for (int c = 0; c < 2; ++c) {
      const int oc = o0 + to + 16 * c;
      float res = acc[r][c].x + acc[r][c].y
                + lout[(tb + 16 * r) * LP + to + 16 * c];
      if (use_ws) {
        partial[(size_t)ks * BO + (size_t)br * OUT_F + oc] = res;
      } else {
        if (ks == 0) res += bias[oc];
        atomicAdd(out + (size_t)br * OUT_F + oc, res);
      }
    }
  }
}

__global__ __launch_bounds__(256)
void wkan_reduce(const float* __restrict__ partial, const float* __restrict__ bias,
                 float* __restrict__ out)
{
  const int i4 = (blockIdx.x * 256 + threadIdx.x) * 4;
  float4 r = *(const float4*)(bias + (i4 & (OUT_F - 1)));
#pragma unroll
  for (int k = 0; k < KS; ++k) {
    float4 a = *(const float4*)(partial + (size_t)k * BO + i4);
    r.x += a.x; r.y += a.y; r.z += a.z; r.w += a.w;
  }
  *(float4*)(out + i4) = r;
}

extern "C" void kernel_launch(void* const* d_in, const int* in_sizes, int n_in,
                              void* d_out, int out_size, void* d_ws, size_t ws_size,
                              hipStream_t stream) {
  const float* x  = (const float*)d_in[0];
  const float* bw = (const float*)d_in[1];
  const float* ww = (const float*)d_in[2];
  const float* sc = (const float*)d_in[3];
  const float* tr = (const float*)d_in[4];
  const float* bi = (const float*)d_in[5];
  float* out = (float*)d_out;

  const int use_ws = ws_size >= (size_t)KS * BO * sizeof(float) ? 1 : 0;
  if (!use_ws) {
    hipMemsetAsync(d_out, 0, (size_t)out_size * sizeof(float), stream);
  }
  dim3 grid(BATCH / BT, OUT_F / OT, KS);  // 8 x 16 x 8 = 1024 blocks, 4/CU
  wkan_main<<<grid, dim3(256), 0, stream>>>(x, bw, ww, sc, tr, bi,
                                            (float*)d_ws, out, use_ws);
  if (use_ws) {
    wkan_reduce<<<dim3(BO / 1024), dim3(256), 0, stream>>>((const float*)d_ws, bi, out);
  }
}